// Round 28
// baseline (114.158 us; speedup 1.0000x reference)
//
#include <hip/hip_runtime.h>
#include <stdint.h>

// FilteredLReLU: up2(17-tap) -> *2 -> lrelu(0.01) -> down2(17-tap), fused.
// R24 wave-shared pk_fma SWAR + async 2-tile pipeline:
//   tile A: register-loaded x (R24 path; compiler waits only on A's loads)
//   tile B: x staged via 2x global_load_lds into a per-wave LDS buffer,
//           issued BEFORE A's compute -> B's HBM latency hides under A.
//           One vmcnt(0)+memory-clobber+sched_barrier before B's reads.
//   B's lanes read windows from LDS (xbuf[8*lane .. 8*lane+15]); lane 63
//   (window past buffer) and halo lanes patch from global.
// Pair buffers separate per tile + wave_barrier fences (R27-proven).
//
//   ge[m] = lrelu( sum fe[j]*x[m-4+j] ), go[m] = lrelu( sum fo[j]*x[m-3+j] )
//   z[t]  = sum de[j]*ge[t-4+j] + sum dd[j]*go[t-4+j]   (UP gain in fe/fo)

#define T_LEN 32768
#define R_OUT 8
#define HALF  16384            // tile-B offset

typedef __fp16   cvt2 __attribute__((ext_vector_type(2)));  // pkrtz result
typedef _Float16 hpair __attribute__((ext_vector_type(2))); // arithmetic

__device__ __forceinline__ uint32_t pkrtz(float lo, float hi) {
    cvt2 p = __builtin_amdgcn_cvt_pkrtz(lo, hi);
    return __builtin_bit_cast(uint32_t, p);
}
__device__ __forceinline__ hpair h2(uint32_t u) {
    return __builtin_bit_cast(hpair, u);
}
__device__ __forceinline__ uint32_t u32(hpair h) {
    return __builtin_bit_cast(uint32_t, h);
}
__device__ __forceinline__ hpair pk_fma(hpair a, hpair b, hpair c) {
    return __builtin_elementwise_fma(a, b, c);
}
__device__ __forceinline__ hpair pk_lrelu(hpair v, hpair c01) {
    return __builtin_elementwise_max(v, v * c01);
}
// async HBM->LDS, 16B/lane: per-lane global src, wave-uniform LDS base;
// HW writes lane L at base + L*16 (verified on-device in R22).
__device__ __forceinline__ void gl_lds16(const float* g, void* l) {
    __builtin_amdgcn_global_load_lds(
        (const __attribute__((address_space(1))) uint32_t*)g,
        (__attribute__((address_space(3))) uint32_t*)l, 16, 0, 0);
}

// ---- setup: broadcast tap pairs once into ws[0..33] ----
// ws[0..8]=feB, ws[9..16]=foB, ws[17..25]=deB, ws[26..33]=ddB
__global__ void pack_taps(const float* __restrict__ up,
                          const float* __restrict__ dn,
                          uint32_t* __restrict__ ws) {
    if (threadIdx.x == 0 && blockIdx.x == 0) {
        #pragma unroll
        for (int j = 0; j < 9; ++j) {
            float fe = 2.0f * up[2*j];
            float de = dn[2*j];
            ws[j]      = pkrtz(fe, fe);
            ws[17 + j] = pkrtz(de, de);
        }
        #pragma unroll
        for (int j = 0; j < 8; ++j) {
            float fo = 2.0f * up[2*j+1];
            float dd = dn[2*j+1];
            ws[9 + j]  = pkrtz(fo, fo);
            ws[26 + j] = pkrtz(dd, dd);
        }
    }
}

// compute 4 (ga, go) pairs for output base tb from xv[16] = x[tb-8 .. tb+7]
__device__ __forceinline__ void pairs4(
    const float* xv, const hpair* feB, const hpair* foB, hpair c01,
    uint32_t* ga, uint32_t* go)
{
    uint32_t xau[8], xsu[7];
    #pragma unroll
    for (int k = 0; k < 8; ++k) xau[k] = pkrtz(xv[2*k], xv[2*k+1]);
    #pragma unroll
    for (int k = 0; k < 7; ++k)
        xsu[k] = (xau[k] >> 16) | (xau[k+1] << 16);   // v_alignbit_b32

    #pragma unroll
    for (int q = 0; q < 4; ++q) {
        hpair s = feB[0] * h2(xau[q]);
        #pragma unroll
        for (int a = 1; a < 5; ++a) s = pk_fma(feB[2*a], h2(xau[q+a]), s);
        #pragma unroll
        for (int a = 0; a < 4; ++a) s = pk_fma(feB[2*a+1], h2(xsu[q+a]), s);
        ga[q] = u32(pk_lrelu(s, c01));

        hpair r = foB[0] * h2(xsu[q]);
        #pragma unroll
        for (int a = 1; a < 4; ++a) r = pk_fma(foB[2*a], h2(xsu[q+a]), r);
        #pragma unroll
        for (int a = 0; a < 4; ++a) r = pk_fma(foB[2*a+1], h2(xau[q+a+1]), r);
        go[q] = u32(pk_lrelu(r, c01));
    }
}

// full tile: own pairs -> LDS[TI], distributed halo, fence, scatter, store
#define PROCESS_TILE(TI, XV, TT)                                             \
{                                                                            \
    uint32_t ga[4], go[4];                                                   \
    pairs4(XV, feB, foB, c01, ga, go);                                       \
    if ((TT) == 0) { ga[0]=0u; go[0]=0u; ga[1]=0u; go[1]=0u; }               \
    *reinterpret_cast<uint4*>(&sga[TI][wv][lane][0]) =                       \
        make_uint4(ga[0], ga[1], ga[2], ga[3]);                              \
    *reinterpret_cast<uint4*>(&sgb[TI][wv][lane][0]) =                       \
        make_uint4(go[0], go[1], go[2], go[3]);                              \
    if (lane >= 60) {                                                        \
        const int q  = lane - 60;                                            \
        const int tx = ((TT) - lane * R_OUT) + 512;                          \
        float xw[12];                                                        \
        if (tx + 2*q + 3 < T_LEN) {                                          \
            const float2* xp2 =                                              \
                reinterpret_cast<const float2*>(xrow + tx - 8 + 2*q);        \
            _Pragma("unroll")                                                \
            for (int k = 0; k < 6; ++k) {                                    \
                float2 v = xp2[k];                                           \
                xw[2*k] = v.x; xw[2*k+1] = v.y;                              \
            }                                                                \
        } else {                                                             \
            _Pragma("unroll")                                                \
            for (int i = 0; i < 12; ++i) {                                   \
                int g = tx - 8 + 2*q + i;                                    \
                xw[i] = (g < T_LEN) ? xrow[g] : 0.0f;                        \
            }                                                                \
        }                                                                    \
        uint32_t hau[5], hsu[4];                                             \
        _Pragma("unroll")                                                    \
        for (int k = 0; k < 5; ++k) hau[k] = pkrtz(xw[2*k], xw[2*k+1]);      \
        _Pragma("unroll")                                                    \
        for (int k = 0; k < 4; ++k)                                          \
            hsu[k] = (hau[k] >> 16) | (hau[k+1] << 16);                      \
        hpair s = feB[0] * h2(hau[0]);                                       \
        _Pragma("unroll")                                                    \
        for (int a = 1; a < 5; ++a) s = pk_fma(feB[2*a], h2(hau[a]), s);     \
        _Pragma("unroll")                                                    \
        for (int a = 0; a < 4; ++a) s = pk_fma(feB[2*a+1], h2(hsu[a]), s);   \
        uint32_t ha = u32(pk_lrelu(s, c01));                                 \
        hpair r = foB[0] * h2(hsu[0]);                                       \
        _Pragma("unroll")                                                    \
        for (int a = 1; a < 4; ++a) r = pk_fma(foB[2*a], h2(hsu[a]), r);     \
        _Pragma("unroll")                                                    \
        for (int a = 0; a < 4; ++a) r = pk_fma(foB[2*a+1], h2(hau[a+1]), r); \
        uint32_t hb = u32(pk_lrelu(r, c01));                                 \
        const int m0 = tx - 4 + 2*q;                                         \
        const uint32_t msk = ((m0   < T_LEN) ? 0x0000FFFFu : 0u)             \
                           | ((m0+1 < T_LEN) ? 0xFFFF0000u : 0u);            \
        sga[TI][wv][64][q] = ha & msk;                                       \
        sgb[TI][wv][64][q] = hb & msk;                                       \
    }                                                                        \
    __builtin_amdgcn_wave_barrier();  /* fence: writes before reads */       \
    {                                                                        \
        uint4 GN = *reinterpret_cast<const uint4*>(&sga[TI][wv][lane+1][0]); \
        uint4 ON = *reinterpret_cast<const uint4*>(&sgb[TI][wv][lane+1][0]); \
        uint32_t gaF[8] = {ga[0],ga[1],ga[2],ga[3],GN.x,GN.y,GN.z,GN.w};     \
        uint32_t goF[8] = {go[0],go[1],go[2],go[3],ON.x,ON.y,ON.z,ON.w};     \
        uint32_t gsh[7], gosh[7];                                            \
        _Pragma("unroll")                                                    \
        for (int k = 0; k < 7; ++k) {                                        \
            gsh[k]  = (gaF[k] >> 16) | (gaF[k+1] << 16);                     \
            gosh[k] = (goF[k] >> 16) | (goF[k+1] << 16);                     \
        }                                                                    \
        hpair zp[4];                                                         \
        _Pragma("unroll")                                                    \
        for (int p = 0; p < 4; ++p) {                                        \
            hpair s = deB[0] * h2(gaF[p]);                                   \
            _Pragma("unroll")                                                \
            for (int a = 1; a < 5; ++a) s = pk_fma(deB[2*a], h2(gaF[p+a]), s); \
            _Pragma("unroll")                                                \
            for (int a = 0; a < 4; ++a) s = pk_fma(deB[2*a+1], h2(gsh[p+a]), s); \
            _Pragma("unroll")                                                \
            for (int a = 0; a < 4; ++a) s = pk_fma(ddB[2*a], h2(goF[p+a]), s); \
            _Pragma("unroll")                                                \
            for (int a = 0; a < 4; ++a) s = pk_fma(ddB[2*a+1], h2(gosh[p+a]), s); \
            zp[p] = s;                                                       \
        }                                                                    \
        float4* op = reinterpret_cast<float4*>(orow + (TT));                 \
        op[0] = make_float4((float)zp[0][0], (float)zp[0][1],                \
                            (float)zp[1][0], (float)zp[1][1]);               \
        op[1] = make_float4((float)zp[2][0], (float)zp[2][1],                \
                            (float)zp[3][0], (float)zp[3][1]);               \
    }                                                                        \
}

__global__ void flrelu_pf2c(
    const float* __restrict__ x,
    const uint32_t* __restrict__ tw,
    float* __restrict__ out)
{
    __shared__ __align__(16) uint32_t sga[2][4][66][4];
    __shared__ __align__(16) uint32_t sgb[2][4][66][4];
    __shared__ __align__(16) float    xbuf[4][528];   // per-wave T1 x (512 + pad)

    const int tid  = threadIdx.x;
    const int lane = tid & 63;
    const int wv   = tid >> 6;
    const int gid  = blockIdx.x * 256 + tid;
    const int row  = gid >> 11;                 // 2048 threads per row
    const int t    = (gid & 2047) * R_OUT;      // tile A base; tile B = t+HALF
    const float* __restrict__ xrow = x + (size_t)row * T_LEN;
    float* __restrict__ orow       = out + (size_t)row * T_LEN;

    // taps: uniform pointer + const idx -> s_loads
    hpair feB[9], foB[8], deB[9], ddB[8];
    #pragma unroll
    for (int j = 0; j < 9; ++j) { feB[j] = h2(tw[j]); deB[j] = h2(tw[17+j]); }
    #pragma unroll
    for (int j = 0; j < 8; ++j) { foB[j] = h2(tw[9+j]); ddB[j] = h2(tw[26+j]); }
    const hpair c01 = h2(pkrtz(0.01f, 0.01f));

    // ---- tile A x into registers (R24 path) ----
    float xvA[16];
    if (t >= 8) {
        const float4* xp = reinterpret_cast<const float4*>(xrow + t - 8);
        float4 v0 = xp[0], v1 = xp[1], v2 = xp[2], v3 = xp[3];
        xvA[0]=v0.x; xvA[1]=v0.y; xvA[2]=v0.z; xvA[3]=v0.w;
        xvA[4]=v1.x; xvA[5]=v1.y; xvA[6]=v1.z; xvA[7]=v1.w;
        xvA[8]=v2.x; xvA[9]=v2.y; xvA[10]=v2.z; xvA[11]=v2.w;
        xvA[12]=v3.x; xvA[13]=v3.y; xvA[14]=v3.z; xvA[15]=v3.w;
    } else {
        #pragma unroll
        for (int i = 0; i < 16; ++i) {
            int g = t - 8 + i;
            xvA[i] = (g >= 0) ? xrow[g] : 0.0f;
        }
    }

    // ---- issue tile B staging: HBM -> LDS, no VGPRs, lands under A ----
    // wave T1 base tB0 = (t - lane*8) + HALF; buffer float i = x[tB0-8+i]
    const int tB0 = (t - lane * R_OUT) + HALF;
    gl_lds16(xrow + (tB0 - 8) + 4 * lane,       &xbuf[wv][0]);
    gl_lds16(xrow + (tB0 - 8) + 256 + 4 * lane, &xbuf[wv][256]);

    // ---- tile A compute (B's loads in flight) ----
    PROCESS_TILE(0, xvA, t)

    // ---- drain B staging, then compute tile B from LDS ----
    asm volatile("s_waitcnt vmcnt(0)" ::: "memory");
    __builtin_amdgcn_sched_barrier(0);

    float xvB[16];
    {
        const float4* lp = reinterpret_cast<const float4*>(&xbuf[wv][8 * lane]);
        float4 w0 = lp[0], w1 = lp[1], w2 = lp[2], w3 = lp[3];
        if (lane == 63) {   // window floats 504..519: 512+ not staged
            const float4* gp =
                reinterpret_cast<const float4*>(xrow + tB0 + 496);
            w0 = gp[0]; w1 = gp[1]; w2 = gp[2]; w3 = gp[3];
        }
        xvB[0]=w0.x; xvB[1]=w0.y; xvB[2]=w0.z; xvB[3]=w0.w;
        xvB[4]=w1.x; xvB[5]=w1.y; xvB[6]=w1.z; xvB[7]=w1.w;
        xvB[8]=w2.x; xvB[9]=w2.y; xvB[10]=w2.z; xvB[11]=w2.w;
        xvB[12]=w3.x; xvB[13]=w3.y; xvB[14]=w3.z; xvB[15]=w3.w;
    }
    PROCESS_TILE(1, xvB, t + HALF)
}

extern "C" void kernel_launch(void* const* d_in, const int* in_sizes, int n_in,
                              void* d_out, int out_size, void* d_ws, size_t ws_size,
                              hipStream_t stream) {
    const float* x  = (const float*)d_in[0];
    const float* up = (const float*)d_in[1];
    const float* dn = (const float*)d_in[2];
    float* out      = (float*)d_out;
    uint32_t* ws    = (uint32_t*)d_ws;

    pack_taps<<<1, 64, 0, stream>>>(up, dn, ws);

    const int rows    = in_sizes[0] / T_LEN;         // 2048
    const int threads = rows * (T_LEN / (2 * R_OUT));// 4.19M
    flrelu_pf2c<<<threads / 256, 256, 0, stream>>>(x, ws, out);
}

// Round 29
// 107.234 us; speedup vs baseline: 1.0646x; 1.0646x over previous
//
#include <hip/hip_runtime.h>
#include <stdint.h>

// FilteredLReLU: up2(17-tap) -> *2 -> lrelu(0.01) -> down2(17-tap), fused.
// FINAL: R24 configuration (session best, 106.8 us).
// Wave-shared pk_fma SWAR, R_OUT=8, distributed halo (lanes 60..63 one
// pair each), per-wave LDS pair sharing (no block barrier), taps packed
// once by a setup kernel into d_ws (uniform s_loads in main kernel).
//
//   ge[m] = lrelu( sum fe[j]*x[m-4+j] ), go[m] = lrelu( sum fo[j]*x[m-3+j] )
//   z[t]  = sum de[j]*ge[t-4+j] + sum dd[j]*go[t-4+j]   (UP gain in fe/fo)

#define T_LEN 32768
#define R_OUT 8

typedef __fp16   cvt2 __attribute__((ext_vector_type(2)));  // pkrtz result
typedef _Float16 hpair __attribute__((ext_vector_type(2))); // arithmetic

__device__ __forceinline__ uint32_t pkrtz(float lo, float hi) {
    cvt2 p = __builtin_amdgcn_cvt_pkrtz(lo, hi);
    return __builtin_bit_cast(uint32_t, p);
}
__device__ __forceinline__ hpair h2(uint32_t u) {
    return __builtin_bit_cast(hpair, u);
}
__device__ __forceinline__ uint32_t u32(hpair h) {
    return __builtin_bit_cast(uint32_t, h);
}
__device__ __forceinline__ hpair pk_fma(hpair a, hpair b, hpair c) {
    return __builtin_elementwise_fma(a, b, c);
}
__device__ __forceinline__ hpair pk_lrelu(hpair v, hpair c01) {
    return __builtin_elementwise_max(v, v * c01);
}

// ---- setup: broadcast tap pairs once into ws[0..33] ----
// ws[0..8]=feB, ws[9..16]=foB, ws[17..25]=deB, ws[26..33]=ddB
__global__ void pack_taps(const float* __restrict__ up,
                          const float* __restrict__ dn,
                          uint32_t* __restrict__ ws) {
    if (threadIdx.x == 0 && blockIdx.x == 0) {
        #pragma unroll
        for (int j = 0; j < 9; ++j) {
            float fe = 2.0f * up[2*j];
            float de = dn[2*j];
            ws[j]      = pkrtz(fe, fe);
            ws[17 + j] = pkrtz(de, de);
        }
        #pragma unroll
        for (int j = 0; j < 8; ++j) {
            float fo = 2.0f * up[2*j+1];
            float dd = dn[2*j+1];
            ws[9 + j]  = pkrtz(fo, fo);
            ws[26 + j] = pkrtz(dd, dd);
        }
    }
}

// compute 4 (ga, go) pairs for output base tb from xv[16] = x[tb-8 .. tb+7]
__device__ __forceinline__ void pairs4(
    const float* xv, const hpair* feB, const hpair* foB, hpair c01,
    uint32_t* ga, uint32_t* go)
{
    uint32_t xau[8], xsu[7];
    #pragma unroll
    for (int k = 0; k < 8; ++k) xau[k] = pkrtz(xv[2*k], xv[2*k+1]);
    #pragma unroll
    for (int k = 0; k < 7; ++k)
        xsu[k] = (xau[k] >> 16) | (xau[k+1] << 16);   // v_alignbit_b32

    #pragma unroll
    for (int q = 0; q < 4; ++q) {
        hpair s = feB[0] * h2(xau[q]);
        #pragma unroll
        for (int a = 1; a < 5; ++a) s = pk_fma(feB[2*a], h2(xau[q+a]), s);
        #pragma unroll
        for (int a = 0; a < 4; ++a) s = pk_fma(feB[2*a+1], h2(xsu[q+a]), s);
        ga[q] = u32(pk_lrelu(s, c01));

        hpair r = foB[0] * h2(xsu[q]);
        #pragma unroll
        for (int a = 1; a < 4; ++a) r = pk_fma(foB[2*a], h2(xsu[q+a]), r);
        #pragma unroll
        for (int a = 0; a < 4; ++a) r = pk_fma(foB[2*a+1], h2(xau[q+a+1]), r);
        go[q] = u32(pk_lrelu(r, c01));
    }
}

__global__ void flrelu_wshare2(
    const float* __restrict__ x,
    const uint32_t* __restrict__ tw,
    float* __restrict__ out)
{
    __shared__ __align__(16) uint32_t sga[4][66][4];   // per-wave, 65 slots used
    __shared__ __align__(16) uint32_t sgb[4][66][4];

    const int tid  = threadIdx.x;
    const int lane = tid & 63;
    const int wv   = tid >> 6;
    const int gid  = blockIdx.x * 256 + tid;
    const int row  = gid >> 12;                 // 4096 threads per row
    const int t    = (gid & 4095) * R_OUT;
    const float* __restrict__ xrow = x + (size_t)row * T_LEN;
    float* __restrict__ orow       = out + (size_t)row * T_LEN;

    // taps: uniform pointer + const idx -> s_loads
    hpair feB[9], foB[8], deB[9], ddB[8];
    #pragma unroll
    for (int j = 0; j < 9; ++j) { feB[j] = h2(tw[j]); deB[j] = h2(tw[17+j]); }
    #pragma unroll
    for (int j = 0; j < 8; ++j) { foB[j] = h2(tw[9+j]); ddB[j] = h2(tw[26+j]); }
    const hpair c01 = h2(pkrtz(0.01f, 0.01f));

    // ---- own 4 ga + 4 go pairs ----
    uint32_t ga[4], go[4];
    {
        float xv[16];   // x[t-8 .. t+7]; t+7 always < T_LEN
        if (t >= 8) {
            const float4* xp = reinterpret_cast<const float4*>(xrow + t - 8);
            float4 v0 = xp[0], v1 = xp[1], v2 = xp[2], v3 = xp[3];
            xv[0]=v0.x; xv[1]=v0.y; xv[2]=v0.z; xv[3]=v0.w;
            xv[4]=v1.x; xv[5]=v1.y; xv[6]=v1.z; xv[7]=v1.w;
            xv[8]=v2.x; xv[9]=v2.y; xv[10]=v2.z; xv[11]=v2.w;
            xv[12]=v3.x; xv[13]=v3.y; xv[14]=v3.z; xv[15]=v3.w;
        } else {
            #pragma unroll
            for (int i = 0; i < 16; ++i) {
                int g = t - 8 + i;
                xv[i] = (g >= 0) ? xrow[g] : 0.0f;
            }
        }
        pairs4(xv, feB, foB, c01, ga, go);
        if (t == 0) {   // ge/go[m]=0 for m<0 (dn conv zero-pads y): q=0,1
            ga[0] = 0u; go[0] = 0u; ga[1] = 0u; go[1] = 0u;
        }
        *reinterpret_cast<uint4*>(&sga[wv][lane][0]) =
            make_uint4(ga[0], ga[1], ga[2], ga[3]);
        *reinterpret_cast<uint4*>(&sgb[wv][lane][0]) =
            make_uint4(go[0], go[1], go[2], go[3]);
    }

    // ---- halo slot 64: lanes 60..63 compute ONE pair each (q = lane-60) ----
    if (lane >= 60) {
        const int q  = lane - 60;
        const int tx = (t - lane * R_OUT) + 512;   // wave halo base; <= T_LEN
        // window: x[tx-8+2q .. tx+3+2q], 12 floats, 8B-aligned (2q even)
        float xw[12];
        if (tx + 2*q + 3 < T_LEN) {
            const float2* xp2 =
                reinterpret_cast<const float2*>(xrow + tx - 8 + 2*q);
            #pragma unroll
            for (int k = 0; k < 6; ++k) {
                float2 v = xp2[k];
                xw[2*k] = v.x; xw[2*k+1] = v.y;
            }
        } else {
            #pragma unroll
            for (int i = 0; i < 12; ++i) {
                int g = tx - 8 + 2*q + i;
                xw[i] = (g < T_LEN) ? xrow[g] : 0.0f;
            }
        }
        uint32_t xau[5], xsu[4];
        #pragma unroll
        for (int k = 0; k < 5; ++k) xau[k] = pkrtz(xw[2*k], xw[2*k+1]);
        #pragma unroll
        for (int k = 0; k < 4; ++k)
            xsu[k] = (xau[k] >> 16) | (xau[k+1] << 16);

        hpair s = feB[0] * h2(xau[0]);
        #pragma unroll
        for (int a = 1; a < 5; ++a) s = pk_fma(feB[2*a], h2(xau[a]), s);
        #pragma unroll
        for (int a = 0; a < 4; ++a) s = pk_fma(feB[2*a+1], h2(xsu[a]), s);
        uint32_t ha = u32(pk_lrelu(s, c01));

        hpair r = foB[0] * h2(xsu[0]);
        #pragma unroll
        for (int a = 1; a < 4; ++a) r = pk_fma(foB[2*a], h2(xsu[a]), r);
        #pragma unroll
        for (int a = 0; a < 4; ++a) r = pk_fma(foB[2*a+1], h2(xau[a+1]), r);
        uint32_t hb = u32(pk_lrelu(r, c01));

        const int m0 = tx - 4 + 2*q;             // >= 508, may exceed T_LEN
        const uint32_t msk = ((m0   < T_LEN) ? 0x0000FFFFu : 0u)
                           | ((m0+1 < T_LEN) ? 0xFFFF0000u : 0u);
        sga[wv][64][q] = ha & msk;
        sgb[wv][64][q] = hb & msk;
    }

    // ---- stage B: own pairs (regs) + neighbor pairs (LDS slot lane+1) ----
    {
        uint4 GN = *reinterpret_cast<const uint4*>(&sga[wv][lane + 1][0]);
        uint4 ON = *reinterpret_cast<const uint4*>(&sgb[wv][lane + 1][0]);
        uint32_t gaF[8] = {ga[0], ga[1], ga[2], ga[3], GN.x, GN.y, GN.z, GN.w};
        uint32_t goF[8] = {go[0], go[1], go[2], go[3], ON.x, ON.y, ON.z, ON.w};

        uint32_t gs[7], gos[7];
        #pragma unroll
        for (int k = 0; k < 7; ++k) {
            gs[k]  = (gaF[k] >> 16) | (gaF[k+1] << 16);
            gos[k] = (goF[k] >> 16) | (goF[k+1] << 16);
        }

        hpair zp[4];
        #pragma unroll
        for (int p = 0; p < 4; ++p) {
            hpair s = deB[0] * h2(gaF[p]);
            #pragma unroll
            for (int a = 1; a < 5; ++a) s = pk_fma(deB[2*a], h2(gaF[p+a]), s);
            #pragma unroll
            for (int a = 0; a < 4; ++a) s = pk_fma(deB[2*a+1], h2(gs[p+a]), s);
            #pragma unroll
            for (int a = 0; a < 4; ++a) s = pk_fma(ddB[2*a], h2(goF[p+a]), s);
            #pragma unroll
            for (int a = 0; a < 4; ++a) s = pk_fma(ddB[2*a+1], h2(gos[p+a]), s);
            zp[p] = s;
        }

        float4* op = reinterpret_cast<float4*>(orow + t);
        op[0] = make_float4((float)zp[0][0], (float)zp[0][1],
                            (float)zp[1][0], (float)zp[1][1]);
        op[1] = make_float4((float)zp[2][0], (float)zp[2][1],
                            (float)zp[3][0], (float)zp[3][1]);
    }
}

extern "C" void kernel_launch(void* const* d_in, const int* in_sizes, int n_in,
                              void* d_out, int out_size, void* d_ws, size_t ws_size,
                              hipStream_t stream) {
    const float* x  = (const float*)d_in[0];
    const float* up = (const float*)d_in[1];
    const float* dn = (const float*)d_in[2];
    float* out      = (float*)d_out;
    uint32_t* ws    = (uint32_t*)d_ws;

    pack_taps<<<1, 64, 0, stream>>>(up, dn, ws);

    const int rows    = in_sizes[0] / T_LEN;         // 2048
    const int threads = rows * (T_LEN / R_OUT);      // 8.39M
    flrelu_wshare2<<<threads / 256, 256, 0, stream>>>(x, ws, out);
}